// Round 3
// baseline (53.687 us; speedup 1.0000x reference)
//
#include <hip/hip_runtime.h>
#include <hip/hip_bf16.h>

// Subpixel / pixel-shuffle, r=2:
//   out[n, 2i+r2, 2j+r1, q] = x[n, i, j, q*4 + r1*2 + r2]
// x: (32, 256, 256, 12) fp32  ->  out: (32, 512, 512, 3) fp32
//
// Two input pixels (i, 2jj) and (i, 2jj+1) per thread:
//   reads : 24 contiguous floats  = 6x 16B vector loads (coalesced)
//   writes: 12 contiguous floats on each of output rows 2i and 2i+1
//           = 3x 16B vector stores per row, 16B-aligned, non-temporal.

#define B  32
#define H  256
#define W  256
#define C  12
#define Q  3
#define OW (W * 2)   // 512

typedef float f4 __attribute__((ext_vector_type(4)));  // native vector: nontemporal-ok

__global__ __launch_bounds__(256) void subpixel_kernel(const float* __restrict__ x,
                                                       float* __restrict__ out) {
    const int idx = blockIdx.x * blockDim.x + threadIdx.x;  // 0 .. B*H*W/2-1
    const int jj = idx & (W / 2 - 1);          // pair index: input cols 2jj, 2jj+1
    const int i  = (idx >> 7) & (H - 1);
    const int n  = idx >> 15;

    const f4* __restrict__ inp = reinterpret_cast<const f4*>(x + (size_t)idx * 2 * C);
    const f4 v0 = inp[0];  // pixel j0: c0..c3   (q0: r1r2=00,01,10,11)
    const f4 v1 = inp[1];  // pixel j0: c4..c7   (q1)
    const f4 v2 = inp[2];  // pixel j0: c8..c11  (q2)
    const f4 v3 = inp[3];  // pixel j1: c0..c3
    const f4 v4 = inp[4];  // pixel j1: c4..c7
    const f4 v5 = inp[5];  // pixel j1: c8..c11

    // output rows 2i (r2=0 -> elems 0/2) and 2i+1 (r2=1 -> elems 1/3), cols 4jj..4jj+3
    float* __restrict__ o0 = out + ((size_t)((n * (H * 2) + 2 * i) * OW + 4 * jj)) * Q;
    float* __restrict__ o1 = o0 + (size_t)OW * Q;

    f4* __restrict__ s0 = reinterpret_cast<f4*>(o0);
    f4* __restrict__ s1 = reinterpret_cast<f4*>(o1);

    // row 2i  : [v0.x v1.x v2.x | v0.z v1.z v2.z | v3.x v4.x v5.x | v3.z v4.z v5.z]
    __builtin_nontemporal_store((f4){v0.x, v1.x, v2.x, v0.z}, &s0[0]);
    __builtin_nontemporal_store((f4){v1.z, v2.z, v3.x, v4.x}, &s0[1]);
    __builtin_nontemporal_store((f4){v5.x, v3.z, v4.z, v5.z}, &s0[2]);
    // row 2i+1: [v0.y v1.y v2.y | v0.w v1.w v2.w | v3.y v4.y v5.y | v3.w v4.w v5.w]
    __builtin_nontemporal_store((f4){v0.y, v1.y, v2.y, v0.w}, &s1[0]);
    __builtin_nontemporal_store((f4){v1.w, v2.w, v3.y, v4.y}, &s1[1]);
    __builtin_nontemporal_store((f4){v5.y, v3.w, v4.w, v5.w}, &s1[2]);
}

extern "C" void kernel_launch(void* const* d_in, const int* in_sizes, int n_in,
                              void* d_out, int out_size, void* d_ws, size_t ws_size,
                              hipStream_t stream) {
    const float* x = (const float*)d_in[0];
    float* out = (float*)d_out;

    const int n_threads = B * H * W / 2;     // 1,048,576
    const int block = 256;
    const int grid = n_threads / block;      // 4096
    subpixel_kernel<<<grid, block, 0, stream>>>(x, out);
}

// Round 4
// 37.610 us; speedup vs baseline: 1.4274x; 1.4274x over previous
//
#include <hip/hip_runtime.h>
#include <hip/hip_bf16.h>

// Subpixel / pixel-shuffle, r=2:
//   out[n, 2i+r2, 2j+r1, q] = x[n, i, j, q*4 + r1*2 + r2]
// x: (32, 256, 256, 12) fp32  ->  out: (32, 512, 512, 3) fp32
//
// Two input pixels (i, 2jj) and (i, 2jj+1) per thread:
//   reads : 24 contiguous floats  = 6x 16B vector loads (coalesced)
//   writes: 12 contiguous floats on each of output rows 2i and 2i+1
//           = 3x 16B vector stores per row, 16B-aligned.
// NOTE: plain stores (NOT nontemporal) — nt defeated L2 write-combining of
// the stride-48 partial-sector pattern and cost +18 us in round 2.

#define B  32
#define H  256
#define W  256
#define C  12
#define Q  3
#define OW (W * 2)   // 512

typedef float f4 __attribute__((ext_vector_type(4)));

__global__ __launch_bounds__(256) void subpixel_kernel(const float* __restrict__ x,
                                                       float* __restrict__ out) {
    const int idx = blockIdx.x * blockDim.x + threadIdx.x;  // 0 .. B*H*W/2-1
    const int jj = idx & (W / 2 - 1);          // pair index: input cols 2jj, 2jj+1
    const int i  = (idx >> 7) & (H - 1);
    const int n  = idx >> 15;

    const f4* __restrict__ inp = reinterpret_cast<const f4*>(x + (size_t)idx * 2 * C);
    const f4 v0 = inp[0];  // pixel j0: c0..c3   (q0: r1r2=00,01,10,11)
    const f4 v1 = inp[1];  // pixel j0: c4..c7   (q1)
    const f4 v2 = inp[2];  // pixel j0: c8..c11  (q2)
    const f4 v3 = inp[3];  // pixel j1: c0..c3
    const f4 v4 = inp[4];  // pixel j1: c4..c7
    const f4 v5 = inp[5];  // pixel j1: c8..c11

    // output rows 2i (r2=0 -> elems 0/2) and 2i+1 (r2=1 -> elems 1/3), cols 4jj..4jj+3
    float* __restrict__ o0 = out + ((size_t)((n * (H * 2) + 2 * i) * OW + 4 * jj)) * Q;
    float* __restrict__ o1 = o0 + (size_t)OW * Q;

    f4* __restrict__ s0 = reinterpret_cast<f4*>(o0);
    f4* __restrict__ s1 = reinterpret_cast<f4*>(o1);

    // row 2i  : [v0.x v1.x v2.x | v0.z v1.z v2.z | v3.x v4.x v5.x | v3.z v4.z v5.z]
    s0[0] = (f4){v0.x, v1.x, v2.x, v0.z};
    s0[1] = (f4){v1.z, v2.z, v3.x, v4.x};
    s0[2] = (f4){v5.x, v3.z, v4.z, v5.z};
    // row 2i+1: [v0.y v1.y v2.y | v0.w v1.w v2.w | v3.y v4.y v5.y | v3.w v4.w v5.w]
    s1[0] = (f4){v0.y, v1.y, v2.y, v0.w};
    s1[1] = (f4){v1.w, v2.w, v3.y, v4.y};
    s1[2] = (f4){v5.y, v3.w, v4.w, v5.w};
}

extern "C" void kernel_launch(void* const* d_in, const int* in_sizes, int n_in,
                              void* d_out, int out_size, void* d_ws, size_t ws_size,
                              hipStream_t stream) {
    const float* x = (const float*)d_in[0];
    float* out = (float*)d_out;

    const int n_threads = B * H * W / 2;     // 1,048,576
    const int block = 256;
    const int grid = n_threads / block;      // 4096
    subpixel_kernel<<<grid, block, 0, stream>>>(x, out);
}

// Round 5
// 35.778 us; speedup vs baseline: 1.5005x; 1.0512x over previous
//
#include <hip/hip_runtime.h>
#include <hip/hip_bf16.h>

// Subpixel / pixel-shuffle, r=2:
//   out[n, 2i+r2, 2j+r1, q] = x[n, i, j, q*4 + r1*2 + r2]
// x: (32, 256, 256, 12) fp32  ->  out: (32, 512, 512, 3) fp32
//
// Round-1 proven layout (1 input pixel per iteration, float4 loads,
// float2 stores — 35.5us), plus grid-stride: 2048 blocks x 256 threads,
// 4 iterations/thread (compile-time trip count -> compiler can pipeline
// next iteration's loads under current stores; kills dispatch tail).
// NOTE: no nontemporal stores — nt cost +18us (round 2).

#define B  32
#define H  256
#define W  256
#define C  12
#define Q  3
#define OW (W * 2)   // 512

#define NPIX   (B * H * W)       // 2,097,152
#define BLOCK  256
#define GRID   2048
#define STRIDE (GRID * BLOCK)    // 524,288
#define ITERS  (NPIX / STRIDE)   // 4

typedef float f4 __attribute__((ext_vector_type(4)));
typedef float f2 __attribute__((ext_vector_type(2)));

__global__ __launch_bounds__(BLOCK) void subpixel_kernel(const float* __restrict__ x,
                                                         float* __restrict__ out) {
    const int tid = blockIdx.x * BLOCK + threadIdx.x;

#pragma unroll
    for (int it = 0; it < ITERS; ++it) {
        const int idx = tid + it * STRIDE;       // input pixel id
        const int j = idx & (W - 1);
        const int i = (idx >> 8) & (H - 1);
        const int n = idx >> 16;

        const f4* __restrict__ inp = reinterpret_cast<const f4*>(x + (size_t)idx * C);
        const f4 v0 = inp[0];  // c0..c3  : q0, (r1,r2)=(0,0),(0,1),(1,0),(1,1)
        const f4 v1 = inp[1];  // c4..c7  : q1
        const f4 v2 = inp[2];  // c8..c11 : q2

        float* __restrict__ o0 = out + ((size_t)((n * (H * 2) + 2 * i) * OW + 2 * j)) * Q;
        float* __restrict__ o1 = o0 + (size_t)OW * Q;

        f2* __restrict__ s0 = reinterpret_cast<f2*>(o0);
        f2* __restrict__ s1 = reinterpret_cast<f2*>(o1);

        // row 2i   (r2=0): [c0, c4, c8,  c2, c6, c10]
        s0[0] = (f2){v0.x, v1.x};
        s0[1] = (f2){v2.x, v0.z};
        s0[2] = (f2){v1.z, v2.z};
        // row 2i+1 (r2=1): [c1, c5, c9,  c3, c7, c11]
        s1[0] = (f2){v0.y, v1.y};
        s1[1] = (f2){v2.y, v0.w};
        s1[2] = (f2){v1.w, v2.w};
    }
}

extern "C" void kernel_launch(void* const* d_in, const int* in_sizes, int n_in,
                              void* d_out, int out_size, void* d_ws, size_t ws_size,
                              hipStream_t stream) {
    const float* x = (const float*)d_in[0];
    float* out = (float*)d_out;
    subpixel_kernel<<<GRID, BLOCK, 0, stream>>>(x, out);
}

// Round 6
// 34.696 us; speedup vs baseline: 1.5474x; 1.0312x over previous
//
#include <hip/hip_runtime.h>
#include <hip/hip_bf16.h>

// Subpixel / pixel-shuffle, r=2:
//   out[n, 2i+r2, 2j+r1, q] = x[n, i, j, q*4 + r1*2 + r2]
// x: (32, 256, 256, 12) fp32  ->  out: (32, 512, 512, 3) fp32
//
// Key fact: input row (n,i) = 3072 contiguous floats at offset blk*3072, and
// its output row-pair (n,2i,:,:)+(n,2i+1,:,:) = 3072 contiguous floats at the
// SAME offset blk*3072. The op is a per-row permutation -> stage it in LDS:
//   phase 1: dense float4 loads of the input row; input f4 unit u holds
//            pixel p=u/3, quad q=u%3, elements e = 2*r1 + r2. Scatter b32
//            into LDS laid out in OUTPUT order: r2*1536 + 6p + 3r1 + q.
//   phase 2: dense float4 copy LDS -> global (row-pair is contiguous).
// Every global memory instruction is now 100% sector-dense (vs 1/3 before).
// Phase-1 LDS write pattern (stride 6 floats) is ~2-way aliased = free;
// phase-2 LDS reads are sequential = free.

#define B  32
#define H  256
#define W  256

typedef float f4 __attribute__((ext_vector_type(4)));

__global__ __launch_bounds__(256) void subpixel_kernel(const float* __restrict__ x,
                                                       float* __restrict__ out) {
    __shared__ float lds[3072];          // one output row-pair (12 KB)

    const int blk = blockIdx.x;          // n*H + i  (0..8191)
    const int t   = threadIdx.x;

    const f4* __restrict__ rowin  = reinterpret_cast<const f4*>(x   + (size_t)blk * 3072);
    f4* __restrict__       rowout = reinterpret_cast<f4*>      (out + (size_t)blk * 3072);

    // phase 1: dense global loads, scatter into output-layout LDS
#pragma unroll
    for (int k = 0; k < 3; ++k) {
        const int u = t + k * 256;       // f4 unit within the input row (0..767)
        const f4 v = rowin[u];
        const int p = u / 3;             // input pixel j   (compiler: magic-mul)
        const int q = u - 3 * p;         // channel quad
        const int b = 6 * p + q;         // output-layout base for (r1=0, r2=0)
        lds[b]        = v.x;             // e=0: r1=0, r2=0 -> row 2i,   col 2j
        lds[b + 1536] = v.y;             // e=1: r1=0, r2=1 -> row 2i+1, col 2j
        lds[b + 3]    = v.z;             // e=2: r1=1, r2=0 -> row 2i,   col 2j+1
        lds[b + 1539] = v.w;             // e=3: r1=1, r2=1 -> row 2i+1, col 2j+1
    }
    __syncthreads();

    // phase 2: dense LDS -> global copy (output row-pair is contiguous)
    const f4* __restrict__ lds4 = reinterpret_cast<const f4*>(lds);
#pragma unroll
    for (int k = 0; k < 3; ++k) {
        const int u = t + k * 256;
        rowout[u] = lds4[u];
    }
}

extern "C" void kernel_launch(void* const* d_in, const int* in_sizes, int n_in,
                              void* d_out, int out_size, void* d_ws, size_t ws_size,
                              hipStream_t stream) {
    const float* x = (const float*)d_in[0];
    float* out = (float*)d_out;

    const int grid = B * H;              // 8192 blocks, one input row each
    subpixel_kernel<<<grid, 256, 0, stream>>>(x, out);
}